// Round 9
// baseline (539.446 us; speedup 1.0000x reference)
//
#include <hip/hip_runtime.h>

// SkipConnection MLP, fp32 VALU (only numerically-viable pipe; fp32 reassoc
// already uses 0.23% of the 2% budget -> bf16/fp16/MFMA dead).
//
// Round-8 fix: tail sequence was STEP(false,97);... which skipped layer 96
// and computed 98 twice (absmax 1.27e10). Corrected to prefetch 96,97,98.
// Mechanism under test (round-6 theory): weights via LDS broadcast + VGPR
// depth-1 double-buffer, instead of the SGPR-ceiling-limited s_load path.

#define NLAYERS 99

__global__ __launch_bounds__(256) void skipmlp_kernel(
    const float* __restrict__ x,      // [B,2]
    const float* __restrict__ W_in,   // [2,4]
    const float* __restrict__ b_in,   // [4]
    const float* __restrict__ Ws,     // [99,4,4]
    const float* __restrict__ bs,     // [99,4]
    const float* __restrict__ W_out,  // [4,1]
    const float* __restrict__ b_out,  // [1]
    float* __restrict__ out,          // [B,1]
    int B)
{
    // LDS layout: [layer][5] float4 = {Wrow0, Wrow1, Wrow2, Wrow3, bias}
    __shared__ float4 lw[NLAYERS * 5];

    const float4* __restrict__ Ws4 = reinterpret_cast<const float4*>(Ws);
    const float4* __restrict__ bs4 = reinterpret_cast<const float4*>(bs);
    for (int j4 = threadIdx.x; j4 < NLAYERS * 5; j4 += 256) {
        int layer = j4 / 5;
        int q = j4 - layer * 5;
        lw[j4] = (q < 4) ? Ws4[layer * 4 + q] : bs4[layer];
    }
    __syncthreads();

    int row = blockIdx.x * blockDim.x + threadIdx.x;
    if (row >= B) return;

    const float2 xv = *reinterpret_cast<const float2*>(x + (size_t)row * 2u);

    // input layer (tiny; SGPR path fine)
    float o0 = fmaxf(fmaf(xv.x, W_in[0], fmaf(xv.y, W_in[4], b_in[0])), 0.f);
    float o1 = fmaxf(fmaf(xv.x, W_in[1], fmaf(xv.y, W_in[5], b_in[1])), 0.f);
    float o2 = fmaxf(fmaf(xv.x, W_in[2], fmaf(xv.y, W_in[6], b_in[2])), 0.f);
    float o3 = fmaxf(fmaf(xv.x, W_in[3], fmaf(xv.y, W_in[7], b_in[3])), 0.f);

    float s0 = o0, s1 = o1, s2 = o2, s3 = o3;

    // current-layer weights in VGPRs
    float4 c0 = lw[0], c1 = lw[1], c2 = lw[2], c3 = lw[3], cb = lw[4];

    // One layer, with depth-1 prefetch of layer (NEXT).
    // RES: o = max(W.o + (b+s), s)   [relu(p)+s == max(p+s,s), s,relu>=0]
    // !RES: o = max(W.o + b, 0)      [b rides as fma-chain init from VGPR]
#define STEP(RES, NEXT) {                                                     \
        float4 n0 = lw[(NEXT)*5+0], n1 = lw[(NEXT)*5+1], n2 = lw[(NEXT)*5+2], \
               n3 = lw[(NEXT)*5+3], nb = lw[(NEXT)*5+4];                      \
        float i0, i1, i2, i3;                                                 \
        if (RES) { i0 = cb.x + s0; i1 = cb.y + s1; i2 = cb.z + s2; i3 = cb.w + s3; } \
        else     { i0 = cb.x;      i1 = cb.y;      i2 = cb.z;      i3 = cb.w; }      \
        float p0 = fmaf(o0, c0.x, fmaf(o1, c1.x, fmaf(o2, c2.x, fmaf(o3, c3.x, i0)))); \
        float p1 = fmaf(o0, c0.y, fmaf(o1, c1.y, fmaf(o2, c2.y, fmaf(o3, c3.y, i1)))); \
        float p2 = fmaf(o0, c0.z, fmaf(o1, c1.z, fmaf(o2, c2.z, fmaf(o3, c3.z, i2)))); \
        float p3 = fmaf(o0, c0.w, fmaf(o1, c1.w, fmaf(o2, c2.w, fmaf(o3, c3.w, i3)))); \
        if (RES) {                                                            \
            o0 = fmaxf(p0, s0); o1 = fmaxf(p1, s1);                           \
            o2 = fmaxf(p2, s2); o3 = fmaxf(p3, s3);                           \
            s0 = o0; s1 = o1; s2 = o2; s3 = o3;                               \
        } else {                                                              \
            o0 = fmaxf(p0, 0.f); o1 = fmaxf(p1, 0.f);                         \
            o2 = fmaxf(p2, 0.f); o3 = fmaxf(p3, 0.f);                         \
        }                                                                     \
        c0 = n0; c1 = n1; c2 = n2; c3 = n3; cb = nb;                          \
    }

    // layers 0..94: 19 blocks of 5 (base%5==0 -> flags are j%5, compile-time).
    // prefetch index base+j+1 <= 95 always valid.
    for (int base = 0; base < 95; base += 5) {
        STEP(false, base + 1);
        STEP(true,  base + 2);
        STEP(true,  base + 3);
        STEP(true,  base + 4);
        STEP(true,  base + 5);
    }
    // tail: c holds layer 95. Compute 95 (plain), 96, 97, 98 (residual);
    // final prefetch is a harmless dummy re-read of 98.
    STEP(false, 96);
    STEP(true,  97);
    STEP(true,  98);
    STEP(true,  98);
#undef STEP

    float y = fmaf(o0, W_out[0], fmaf(o1, W_out[1], fmaf(o2, W_out[2], o3 * W_out[3]))) + b_out[0];
    out[row] = y;
}

extern "C" void kernel_launch(void* const* d_in, const int* in_sizes, int n_in,
                              void* d_out, int out_size, void* d_ws, size_t ws_size,
                              hipStream_t stream) {
    const float* x     = (const float*)d_in[0];
    const float* W_in  = (const float*)d_in[1];
    const float* b_in  = (const float*)d_in[2];
    const float* Ws    = (const float*)d_in[3];
    const float* bs    = (const float*)d_in[4];
    const float* W_out = (const float*)d_in[5];
    const float* b_out = (const float*)d_in[6];
    float* out = (float*)d_out;

    const int B = in_sizes[0] / 2;  // x is [B,2]
    const int block = 256;
    const int grid = (B + block - 1) / block;

    skipmlp_kernel<<<grid, block, 0, stream>>>(x, W_in, b_in, Ws, bs, W_out, b_out, out, B);
}

// Round 10
// 464.624 us; speedup vs baseline: 1.1610x; 1.1610x over previous
//
#include <hip/hip_runtime.h>

// SkipConnection MLP, fp32 VALU, round-10: identity-fold.
// After any residual layer skip==out, so layers i%5 in {2,3,4} (59 of 99)
// satisfy: o' = relu(oW+b)+o = max((W+I)o + b, o). Prep kernel writes
// W' = W+I for those layers into d_ws. Biases live in LDS (99 float4),
// one broadcast ds_read per layer, riding as the fma-chain init.
// Per-layer VALU: plain 20, unfolded-res 24, folded-res 20 (was 24 each).

#define NLAYERS 99

__global__ void prep_kernel(const float* __restrict__ Ws,
                            const float* __restrict__ bs,
                            float* __restrict__ wmod) {
    int i = blockIdx.x * blockDim.x + threadIdx.x;
    if (i < NLAYERS * 16) {
        int layer = i >> 4;
        int e = i & 15;                      // e = j*4+c in W[j][c]
        float w = Ws[i];
        if ((layer % 5) >= 2 && (e % 5) == 0) w += 1.0f;  // diagonal j==c
        wmod[i] = w;
    }
    if (i < NLAYERS * 4) wmod[NLAYERS * 16 + i] = bs[i];
}

__global__ __launch_bounds__(256) void skipmlp_kernel(
    const float* __restrict__ x,      // [B,2]
    const float* __restrict__ W_in,   // [2,4]
    const float* __restrict__ b_in,   // [4]
    const float* __restrict__ wmod,   // [99*16 W' | 99*4 b] in d_ws
    const float* __restrict__ W_out,  // [4,1]
    const float* __restrict__ b_out,  // [1]
    float* __restrict__ out,          // [B,1]
    int B)
{
    __shared__ float4 lb[NLAYERS];    // biases, broadcast-read
    if (threadIdx.x < NLAYERS)
        lb[threadIdx.x] =
            reinterpret_cast<const float4*>(wmod + NLAYERS * 16)[threadIdx.x];
    __syncthreads();

    int row = blockIdx.x * blockDim.x + threadIdx.x;
    if (row >= B) return;

    const float2 xv = *reinterpret_cast<const float2*>(x + (size_t)row * 2u);

    // input layer (SGPR path)
    float o0 = fmaxf(fmaf(xv.x, W_in[0], fmaf(xv.y, W_in[4], b_in[0])), 0.f);
    float o1 = fmaxf(fmaf(xv.x, W_in[1], fmaf(xv.y, W_in[5], b_in[1])), 0.f);
    float o2 = fmaxf(fmaf(xv.x, W_in[2], fmaf(xv.y, W_in[6], b_in[2])), 0.f);
    float o3 = fmaxf(fmaf(xv.x, W_in[3], fmaf(xv.y, W_in[7], b_in[3])), 0.f);

    float s0 = o0, s1 = o1, s2 = o2, s3 = o3;

    float4 bc = lb[0];   // current layer's bias (rotated)

    // MODE: 0 = plain (i%5==0): o' = max(W.o + b, 0), s preserved.
    //       1 = unfolded residual (i%5==1, s != o): o' = max(W.o + (b+s), s).
    //       2 = folded residual (i%5 in {2,3,4}, s == o): W' = W+I:
    //           o' = max(W'.o + b, o).  s' = o' (SSA rename, no mov).
#define STEP(MODE, I, NEXT) {                                                 \
        float4 bn = lb[NEXT];                                                 \
        const float* __restrict__ W = wmod + (I) * 16;                        \
        float i0, i1, i2, i3;                                                 \
        if (MODE == 1) { i0 = bc.x + s0; i1 = bc.y + s1;                      \
                         i2 = bc.z + s2; i3 = bc.w + s3; }                    \
        else           { i0 = bc.x; i1 = bc.y; i2 = bc.z; i3 = bc.w; }        \
        float p0 = fmaf(o0, W[ 0], fmaf(o1, W[ 4], fmaf(o2, W[ 8], fmaf(o3, W[12], i0)))); \
        float p1 = fmaf(o0, W[ 1], fmaf(o1, W[ 5], fmaf(o2, W[ 9], fmaf(o3, W[13], i1)))); \
        float p2 = fmaf(o0, W[ 2], fmaf(o1, W[ 6], fmaf(o2, W[10], fmaf(o3, W[14], i2)))); \
        float p3 = fmaf(o0, W[ 3], fmaf(o1, W[ 7], fmaf(o2, W[11], fmaf(o3, W[15], i3)))); \
        if (MODE == 0) {                                                      \
            o0 = fmaxf(p0, 0.f); o1 = fmaxf(p1, 0.f);                         \
            o2 = fmaxf(p2, 0.f); o3 = fmaxf(p3, 0.f);                         \
        } else if (MODE == 1) {                                               \
            o0 = fmaxf(p0, s0); o1 = fmaxf(p1, s1);                           \
            o2 = fmaxf(p2, s2); o3 = fmaxf(p3, s3);                           \
            s0 = o0; s1 = o1; s2 = o2; s3 = o3;                               \
        } else {                                                              \
            o0 = fmaxf(p0, o0); o1 = fmaxf(p1, o1);                           \
            o2 = fmaxf(p2, o2); o3 = fmaxf(p3, o3);                           \
            s0 = o0; s1 = o1; s2 = o2; s3 = o3;                               \
        }                                                                     \
        bc = bn;                                                              \
    }

    // layers 0..94 in 19 blocks of 5 (base%5==0 -> modes are j%5-determined)
    for (int base = 0; base < 95; base += 5) {
        STEP(0, base + 0, base + 1);
        STEP(1, base + 1, base + 2);
        STEP(2, base + 2, base + 3);
        STEP(2, base + 3, base + 4);
        STEP(2, base + 4, base + 5);
    }
    // tail: 95 plain, 96 unfolded, 97 folded, 98 folded (last NEXT dummy)
    STEP(0, 95, 96);
    STEP(1, 96, 97);
    STEP(2, 97, 98);
    STEP(2, 98, 98);
#undef STEP

    float y = fmaf(o0, W_out[0], fmaf(o1, W_out[1], fmaf(o2, W_out[2], o3 * W_out[3]))) + b_out[0];
    out[row] = y;
}

extern "C" void kernel_launch(void* const* d_in, const int* in_sizes, int n_in,
                              void* d_out, int out_size, void* d_ws, size_t ws_size,
                              hipStream_t stream) {
    const float* x     = (const float*)d_in[0];
    const float* W_in  = (const float*)d_in[1];
    const float* b_in  = (const float*)d_in[2];
    const float* Ws    = (const float*)d_in[3];
    const float* bs    = (const float*)d_in[4];
    const float* W_out = (const float*)d_in[5];
    const float* b_out = (const float*)d_in[6];
    float* out = (float*)d_out;
    float* wmod = (float*)d_ws;   // [99*16 + 99*4] floats

    const int B = in_sizes[0] / 2;  // x is [B,2]

    prep_kernel<<<(NLAYERS * 16 + 255) / 256, 256, 0, stream>>>(Ws, bs, wmod);

    const int block = 256;
    const int grid = (B + block - 1) / block;
    skipmlp_kernel<<<grid, block, 0, stream>>>(x, W_in, b_in, wmod, W_out, b_out, out, B);
}